// Round 8
// baseline (212.881 us; speedup 1.0000x reference)
//
#include <hip/hip_runtime.h>

#define B_ 4
#define S_ 4096
#define T_ 4096
#define NH_ 16
#define CPB 64             // columns per block -> 256B per row-visit per plane
#define CPW 4              // columns per wave (16 waves)
#define ROWS 64            // s-rows per LDS tile
#define SSPAN 2048         // s-rows per block
#define NSPAN 2            // s-spans per column
#define NT (SSPAN / ROWS)  // 32 tiles per block
#define LDSP 65            // padded LDS row stride (dwords); 65%32==1 -> conflict-free
#define NCG (T_ / CPB)     // 64 column groups per batch

typedef unsigned long long u64;

// ---------------- Kernel A: transposed top-16 scan, d2-in-LDS, 256B rows ----------------
// grid = B * NCG * NSPAN = 512 blocks x 1024 threads = 2 blocks/CU = 8 waves/SIMD.
// Staging thread (row=tid>>4, col4=(tid&15)*4) loads cx4+cy4, stores 4 d2 to LDS.
// Wave w consumes cols w*4..w*4+3; lanes = 64 s-rows of one column (ballot skip).
__global__ __launch_bounds__(1024, 8) void topk_scan(
    const float* __restrict__ coords,   // [2][B][S][T]
    float* __restrict__ pv,             // [512][NH][64] partial d2, ascending
    unsigned short* __restrict__ pi)    // [512][NH][64] partial global s-idx
{
    __shared__ float lds[2][ROWS * LDSP];   // d2 only; 2 x 16.6 KB

    const int bid  = blockIdx.x;
    const int b    = bid >> 7;
    const int rem  = bid & 127;
    const int cgl  = rem >> 1;          // column group [0,64)
    const int span = rem & 1;
    const int tid  = threadIdx.x;
    const int w    = tid >> 6;
    const int lane = tid & 63;

    const size_t plane = (size_t)B_ * S_ * T_;
    const int srow = tid >> 4;          // [0,64)
    const int scol = (tid & 15) * 4;    // [0,64)
    const int c0   = cgl * CPB;
    const int s0   = span * SSPAN;
    const float* g0 = coords + (size_t)b * S_ * T_ + (size_t)(s0 + srow) * T_ + (c0 + scol);
    const float* g1 = g0 + plane;
    float* w0 = &lds[0][srow * LDSP + scol];
    float* w1 = &lds[1][srow * LDSP + scol];

    float lv[CPW]; int li[CPW]; float tau[CPW];
#pragma unroll
    for (int cc = 0; cc < CPW; ++cc) {
        lv[cc]  = __int_as_float(0x7f800000);
        li[cc]  = 0;
        tau[cc] = __int_as_float(0x7f800000);
    }

    // prologue: tile 0 -> buf0, prefetch tile 1 into regs
    float4 ax = *(const float4*)g0;
    float4 ay = *(const float4*)g1;
    w0[0] = __fadd_rn(__fmul_rn(ax.x, ax.x), __fmul_rn(ay.x, ay.x));
    w0[1] = __fadd_rn(__fmul_rn(ax.y, ax.y), __fmul_rn(ay.y, ay.y));
    w0[2] = __fadd_rn(__fmul_rn(ax.z, ax.z), __fmul_rn(ay.z, ay.z));
    w0[3] = __fadd_rn(__fmul_rn(ax.w, ax.w), __fmul_rn(ay.w, ay.w));
    ax = *(const float4*)(g0 + (size_t)ROWS * T_);
    ay = *(const float4*)(g1 + (size_t)ROWS * T_);
    __syncthreads();                          // buf0 visible

#pragma unroll 1
    for (int k = 0; k < NT; ++k) {
        // stage tile k+1 (in regs) into buf[(k+1)&1]; issue loads of tile k+2
        if (k + 1 < NT) {
            float* wb = (k & 1) ? w0 : w1;
            wb[0] = __fadd_rn(__fmul_rn(ax.x, ax.x), __fmul_rn(ay.x, ay.x));
            wb[1] = __fadd_rn(__fmul_rn(ax.y, ax.y), __fmul_rn(ay.y, ay.y));
            wb[2] = __fadd_rn(__fmul_rn(ax.z, ax.z), __fmul_rn(ay.z, ay.z));
            wb[3] = __fadd_rn(__fmul_rn(ax.w, ax.w), __fmul_rn(ay.w, ay.w));
        }
        if (k + 2 < NT) {
            ax = *(const float4*)(g0 + (size_t)(k + 2) * ROWS * T_);
            ay = *(const float4*)(g1 + (size_t)(k + 2) * ROWS * T_);
        }

        // consume tile k
        const float* rb = lds[k & 1];
        float d2v[CPW];
#pragma unroll
        for (int cc = 0; cc < CPW; ++cc)
            d2v[cc] = rb[lane * LDSP + (w * CPW + cc)];
#pragma unroll
        for (int cc = 0; cc < CPW; ++cc) {
            const float d2 = d2v[cc];
            u64 m = __ballot(d2 < tau[cc]);
            while (m) {                       // wave-uniform scalar loop
                const int src = __ffsll(m) - 1;   // lowest lane = smallest s (tie order)
                m &= m - 1;
                const float cd = __shfl(d2, src);
                const int   ci = s0 + k * ROWS + src;
                const unsigned pm = (unsigned)__ballot(lv[cc] <= cd) & 0xFFFFu;
                const int p = __popc(pm);
                const float uv = __shfl_up(lv[cc], 1);
                const int   ui = __shfl_up(li[cc], 1);
                const bool here  = (lane == p);
                const bool shift = (lane > p) && (lane < NH_);
                lv[cc] = here ? cd : (shift ? uv : lv[cc]);
                li[cc] = here ? ci : (shift ? ui : li[cc]);
                tau[cc] = __shfl(lv[cc], NH_ - 1);
                m &= __ballot(d2 < tau[cc]);
            }
        }
        __syncthreads();                      // buf[(k+1)&1] staged; buf[k&1] free
    }

    // epilogue: lanes<16 write partial lists (slot = lane)
#pragma unroll
    for (int cc = 0; cc < CPW; ++cc) {
        if (lane < NH_) {
            const size_t base = ((size_t)bid * NH_ + lane) * 64 + (w * CPW + cc);
            pv[base] = lv[cc];
            pi[base] = (unsigned short)li[cc];
        }
    }
}

// ---------------- Kernel B: merge 2 spans/column + w + denom partials ----------------
__global__ __launch_bounds__(256) void topk_merge(
    const float* __restrict__ pv, const unsigned short* __restrict__ pi,
    float* __restrict__ outW,           // [B][T][NH]
    int*   __restrict__ outI,
    float* __restrict__ partials)       // [64 blocks][NH]
{
    __shared__ float red[NH_ * 257];

    const int gc  = blockIdx.x * 256 + threadIdx.x;  // [0, B*T)
    const int b   = gc >> 12;
    const int t   = gc & 4095;
    const int cgl = t >> 6;
    const int cl  = t & 63;
    const int bid0 = ((b << 6) | cgl) << 1;

    float cv[NH_]; int ci[NH_];
#pragma unroll
    for (int j = 0; j < NH_; ++j) { cv[j] = __int_as_float(0x7f800000); ci[j] = 0; }

    for (int sp = 0; sp < NSPAN; ++sp) {
        const size_t base = ((size_t)(bid0 + sp) * NH_) * 64 + cl;
        for (int j = 0; j < NH_; ++j) {
            float v = pv[base + (size_t)j * 64];
            if (!(v < cv[NH_ - 1])) break;   // ascending spans: stable ties
            int vi = (int)pi[base + (size_t)j * 64];
#pragma unroll
            for (int q = 0; q < NH_; ++q) {
                bool sw = v < cv[q];
                float tv = cv[q]; int ti = ci[q];
                cv[q] = sw ? v : tv;  ci[q] = sw ? vi : ti;
                v = sw ? tv : v;      vi = sw ? ti : vi;
            }
        }
    }

    const size_t obase = (size_t)gc * NH_;
#pragma unroll
    for (int j = 0; j < NH_; ++j) {
        const float d = sqrtf(cv[j]) + 1e-15f;
        const float wv = 1.0f / (d * d);
        outW[obase + j] = wv;
        outI[obase + j] = ci[j];
        red[j * 257 + threadIdx.x] = wv;
    }
    __syncthreads();
    if (threadIdx.x < NH_) {
        float s = 0.f;
        for (int i = 0; i < 256; ++i) s += red[threadIdx.x * 257 + i];
        partials[(size_t)blockIdx.x * NH_ + threadIdx.x] = s;
    }
}

// ---------------- Kernel C: denom[b][nh] = sum of merge-block partials ----------------
__global__ __launch_bounds__(64) void denom_reduce(
    const float* __restrict__ partials, float* __restrict__ denom)
{
    const int q = threadIdx.x;          // [0,64)
    const int b = q >> 4, j = q & 15;
    float s = 0.f;
    for (int i = 0; i < 16; ++i)        // 16 merge blocks per batch
        s += partials[(size_t)(b * 16 + i) * NH_ + j];
    denom[q] = s;
}

// ---------------- Kernel D: final gather, 16 threads/output ----------------
__global__ __launch_bounds__(256) void out_kernel(
    const float* __restrict__ x,        // [B][S]
    const float* __restrict__ outW,
    const int*   __restrict__ outI,
    const float* __restrict__ denom,    // [B][NH]
    float* __restrict__ out)            // [B][T]
{
    const int gid16 = blockIdx.x * 256 + threadIdx.x;  // [0, 16*B*T)
    const int oid = gid16 >> 4;
    const int q   = gid16 & 15;
    const int i = oid >> 12;
    const int j = oid & 4095;
    const int ih = j >> 8;
    const size_t base = ((size_t)i * T_ + (size_t)(j & 255) * NH_) * NH_ + ih;
    const float w  = outW[base + (size_t)q * NH_];
    const int   id = outI[base + (size_t)q * NH_];
    float v = x[i * S_ + id] * w / denom[(j & 3) * NH_ + q];
    v += __shfl_xor(v, 1);
    v += __shfl_xor(v, 2);
    v += __shfl_xor(v, 4);
    v += __shfl_xor(v, 8);
    if (q == 0) out[oid] = v;
}

extern "C" void kernel_launch(void* const* d_in, const int* in_sizes, int n_in,
                              void* d_out, int out_size, void* d_ws, size_t ws_size,
                              hipStream_t stream) {
    const float* x      = (const float*)d_in[0];
    const float* coords = (const float*)d_in[1];
    float* out = (float*)d_out;

    const int nsb = B_ * NCG * NSPAN;                                // 512 scan blocks
    float*          pv       = (float*)d_ws;                                        // 2 MB
    unsigned short* pi       = (unsigned short*)(pv + (size_t)nsb * NH_ * 64);      // 1 MB
    float*          outW     = (float*)(pi + (size_t)nsb * NH_ * 64);               // 1 MB
    int*            outI     = (int*)(outW + (size_t)B_ * T_ * NH_);                // 1 MB
    float*          partials = (float*)(outI + (size_t)B_ * T_ * NH_);              // 4 KB
    float*          denom    = partials + (size_t)64 * NH_;                         // 256 B

    topk_scan   <<<nsb,                1024, 0, stream>>>(coords, pv, pi);
    topk_merge  <<<B_ * T_ / 256,      256,  0, stream>>>(pv, pi, outW, outI, partials);
    denom_reduce<<<1,                  64,   0, stream>>>(partials, denom);
    out_kernel  <<<B_ * T_ * 16 / 256, 256,  0, stream>>>(x, outW, outI, denom, out);
}

// Round 9
// 159.247 us; speedup vs baseline: 1.3368x; 1.3368x over previous
//
#include <hip/hip_runtime.h>

#define B_ 4
#define S_ 4096
#define T_ 4096
#define NH_ 16
#define CPB 32             // columns per block (128B rows)
#define CPW 2              // columns per wave (16 waves)
#define ROWS 64            // s-rows per tile
#define NT (S_ / ROWS)     // 64 tiles
#define NBUF 4             // LDS ring: depth-2 prefetch + WAR safety (NBUF >= D+2)
#define NCG (T_ / CPB)     // 128 column groups

typedef unsigned long long u64;
typedef const float __attribute__((address_space(1)))* gas1f;
typedef float __attribute__((address_space(3)))* las3f;

// ---------------- Kernel A: transposed top-16 scan, counted-vmcnt pipeline ----------------
// grid = B * NCG = 512 blocks x 1024 threads = 2 blocks/CU = 8 waves/SIMD.
// Staging via global_load_lds (no VGPR round-trip): wave w stages 1KB/tile =
// plane (w>>3), rows (w&7)*8 + (lane>>3), 16B chunk ((lane&7) XOR (lane>>3)) --
// the XOR pre-swizzles the GLOBAL source so the linear LDS dest ends up
// chunk-swizzled (rule: linear dest + inverse-swz source + swz read).
// Sync: raw s_barrier with s_waitcnt vmcnt(2) -- tile k's load done, k+1/k+2
// stay IN FLIGHT across the barrier (no vmcnt(0) drain, unlike __syncthreads).
__global__ __launch_bounds__(1024, 8) void topk_scan(
    const float* __restrict__ coords,   // [2][B][S][T]
    float* __restrict__ outW,           // [B][T][NH]
    int*   __restrict__ outI,           // [B][T][NH]
    float* __restrict__ partials)       // [512][NH]
{
    __shared__ float lds[NBUF * 2 * ROWS * CPB];   // 4 bufs x (2 planes x 64 x 32) = 64 KB
    __shared__ float red[16 * NH_];

    const int bid  = blockIdx.x;
    const int b    = bid >> 7;
    const int c0   = (bid & (NCG - 1)) * CPB;
    const int tid  = threadIdx.x;
    const int w    = tid >> 6;
    const int lane = tid & 63;

    const size_t plane = (size_t)B_ * S_ * T_;
    const int srow   = ((w & 7) << 3) + (lane >> 3);        // row within tile [0,64)
    const int schunk = (lane & 7) ^ (lane >> 3);            // swizzled 16B chunk [0,8)
    const float* gtile = coords + (size_t)(w >> 3) * plane
                       + ((size_t)b * S_ + srow) * T_ + (c0 + schunk * 4);

    // lane-distributed sorted lists: lane j (<16) holds slot j of each owned column
    float lv[CPW]; int li[CPW]; float tau[CPW];
#pragma unroll
    for (int cc = 0; cc < CPW; ++cc) {
        lv[cc]  = __int_as_float(0x7f800000);
        li[cc]  = 0;
        tau[cc] = __int_as_float(0x7f800000);
    }

#define ISSUE(kk) do {                                                         \
    const float* gsrc_ = gtile + (size_t)(kk) * ROWS * T_;                     \
    las3f ldst_ = (las3f)((char*)lds + (((kk) & 3) << 14) + (w << 10));        \
    __builtin_amdgcn_global_load_lds((gas1f)gsrc_, ldst_, 16, 0, 0);           \
} while (0)

    ISSUE(0);
    ISSUE(1);

#pragma unroll 1
    for (int k = 0; k < NT; ++k) {
        if (k + 2 < NT) ISSUE(k + 2);           // buf[(k+2)&3]: consumed at k-2, all
                                                // waves passed barrier(k-1) -> WAR-safe
        if (k + 2 < NT)      asm volatile("s_waitcnt vmcnt(2)" ::: "memory");
        else if (k + 1 < NT) asm volatile("s_waitcnt vmcnt(1)" ::: "memory");
        else                 asm volatile("s_waitcnt vmcnt(0)" ::: "memory");
        __builtin_amdgcn_sched_barrier(0);
        __builtin_amdgcn_s_barrier();           // raw: k+1/k+2 loads stay in flight
        __builtin_amdgcn_sched_barrier(0);

        const float* rb = lds + ((k & 3) << 12);            // 4096 floats per buf
#pragma unroll
        for (int cc = 0; cc < CPW; ++cc) {
            const int c  = w * CPW + cc;
            const int sw = (((c >> 2) ^ (lane & 7)) << 2) + (c & 3);  // read-side swizzle
            const float dx = rb[(lane << 5) + sw];
            const float dy = rb[2048 + (lane << 5) + sw];
            const float d2 = __fadd_rn(__fmul_rn(dx, dx), __fmul_rn(dy, dy));
            u64 m = __ballot(d2 < tau[cc]);
            while (m) {                         // wave-uniform scalar loop
                const int src = __ffsll(m) - 1;     // lowest lane = smallest s (tie order)
                m &= m - 1;
                const float cd = __shfl(d2, src);
                const int   ci = k * ROWS + src;
                const unsigned pm = (unsigned)__ballot(lv[cc] <= cd) & 0xFFFFu;
                const int p = __popc(pm);
                const float uv = __shfl_up(lv[cc], 1);
                const int   ui = __shfl_up(li[cc], 1);
                const bool here  = (lane == p);
                const bool shift = (lane > p) && (lane < NH_);
                lv[cc] = here ? cd : (shift ? uv : lv[cc]);
                li[cc] = here ? ci : (shift ? ui : li[cc]);
                tau[cc] = __shfl(lv[cc], NH_ - 1);
                m &= __ballot(d2 < tau[cc]);    // prune vs tightened threshold
            }
        }
    }
#undef ISSUE

    // epilogue: write lists + per-wave denom partials
    float dsum = 0.f;
#pragma unroll
    for (int cc = 0; cc < CPW; ++cc) {
        const int t = c0 + w * CPW + cc;
        if (lane < NH_) {
            const float d = sqrtf(lv[cc]) + 1e-15f;
            const float wv = 1.0f / (d * d);
            outW[((size_t)b * T_ + t) * NH_ + lane] = wv;
            outI[((size_t)b * T_ + t) * NH_ + lane] = li[cc];
            dsum += wv;
        }
    }
    if (lane < NH_) red[w * NH_ + lane] = dsum;
    __syncthreads();
    if (tid < NH_) {
        float s = 0.f;
#pragma unroll
        for (int q = 0; q < 16; ++q) s += red[q * NH_ + tid];
        partials[(size_t)bid * NH_ + tid] = s;
    }
}

// ---------------- Kernel B: denom[b][nh] = sum of block partials ----------------
__global__ __launch_bounds__(128) void denom_reduce(
    const float* __restrict__ partials, float* __restrict__ denom)
{
    const int q = blockIdx.x;       // [0,64)
    const int b = q >> 4, j = q & 15;
    const int g = threadIdx.x;      // [0,128) = NCG
    __shared__ float sm[128];
    sm[g] = partials[(size_t)(b * NCG + g) * NH_ + j];
    __syncthreads();
    for (int s = 64; s > 0; s >>= 1) {
        if (g < s) sm[g] += sm[g + s];
        __syncthreads();
    }
    if (g == 0) denom[q] = sm[0];
}

// ---------------- Kernel C: final gather + weighted sum ----------------
__global__ __launch_bounds__(256) void out_kernel(
    const float* __restrict__ x,        // [B][S]
    const float* __restrict__ outW,
    const int*   __restrict__ outI,
    const float* __restrict__ denom,    // [B][NH]
    float* __restrict__ out)            // [B][T]
{
    const int gid = blockIdx.x * 256 + threadIdx.x;  // [0, B*T)
    const int i = gid >> 12;
    const int j = gid & 4095;
    const int ih = j >> 8;
    const size_t base = ((size_t)i * T_ + (size_t)(j & 255) * NH_) * NH_ + ih;
    const int dq = (j & 3) * NH_;
    float acc = 0.f;
#pragma unroll
    for (int k = 0; k < NH_; ++k) {
        float w  = outW[base + (size_t)k * NH_];
        int   id = outI[base + (size_t)k * NH_];
        acc += x[i * S_ + id] * w / denom[dq + k];
    }
    out[gid] = acc;
}

extern "C" void kernel_launch(void* const* d_in, const int* in_sizes, int n_in,
                              void* d_out, int out_size, void* d_ws, size_t ws_size,
                              hipStream_t stream) {
    const float* x      = (const float*)d_in[0];
    const float* coords = (const float*)d_in[1];
    float* out = (float*)d_out;

    float* outW     = (float*)d_ws;                                  // 1 MB
    int*   outI     = (int*)(outW + (size_t)B_ * T_ * NH_);          // 1 MB
    float* partials = (float*)(outI + (size_t)B_ * T_ * NH_);        // 32 KB
    float* denom    = partials + (size_t)(B_ * NCG) * NH_;           // 256 B

    topk_scan   <<<B_ * NCG,      1024, 0, stream>>>(coords, outW, outI, partials);
    denom_reduce<<<64,            128,  0, stream>>>(partials, denom);
    out_kernel  <<<B_ * T_ / 256, 256,  0, stream>>>(x, outW, outI, denom, out);
}

// Round 10
// 144.784 us; speedup vs baseline: 1.4703x; 1.0999x over previous
//
#include <hip/hip_runtime.h>

#define B_ 4
#define S_ 4096
#define T_ 4096
#define NH_ 16
#define CPB 32             // columns per block = 128B rows (full cache lines)
#define CPW 2              // columns per wave (16 waves/block)
#define ROWS 64            // s-rows per LDS tile
#define NTILE (S_ / ROWS)  // 64
#define LDSP 33            // padded LDS row stride (dwords); odd -> bank permutation
#define NCG (T_ / CPB)     // 128 column groups

typedef unsigned long long u64;

// DPP row_shr:1 — shift by one lane within each 16-lane row (VALU-only, replaces
// ds_permute-based __shfl_up on the serial insert critical path). Only lanes 0-15
// are consumed (list slots); other lanes' results are masked off by `shift`.
__device__ __forceinline__ float dpp_shr1_f(float v) {
    return __int_as_float(__builtin_amdgcn_update_dpp(
        0, __float_as_int(v), 0x111 /*row_shr:1*/, 0xF, 0xF, true));
}
__device__ __forceinline__ int dpp_shr1_i(int v) {
    return __builtin_amdgcn_update_dpp(0, v, 0x111, 0xF, 0xF, true);
}

// ---------------- Kernel A: transposed top-16 scan, double-buffered ----------------
// grid = B * NCG = 512 blocks x 1024 threads (16 waves) = 2 blocks/CU = 8 waves/SIMD
// (32 waves/CU = HW cap). LDS double buffer: consume buf[k&1] while staging
// buf[(k+1)&1] and issuing the global load for tile k+2.
__global__ __launch_bounds__(1024, 8) void topk_scan(
    const float* __restrict__ coords,   // [2][B][S][T]
    float* __restrict__ outW,           // [B][T][NH]
    int*   __restrict__ outI,           // [B][T][NH]
    float* __restrict__ partials)       // [512][NH] per-block denom partials
{
    __shared__ float lds[2][2][ROWS * LDSP];   // [buf][plane][row*LDSP+col]
    __shared__ float red[16 * NH_];

    const int bid  = blockIdx.x;
    const int b    = bid >> 7;
    const int c0   = (bid & (NCG - 1)) * CPB;
    const int tid  = threadIdx.x;
    const int w    = tid >> 6;
    const int lane = tid & 63;

    const size_t plane = (size_t)B_ * S_ * T_;
    // staging map: stid in [0,512): row = stid>>3, col4 = (stid&7)*4.
    // 8 consecutive threads = one 128B contiguous aligned line.
    const int stid = tid & 511;
    const int srow = stid >> 3;
    const int scol = (stid & 7) * 4;
    const int pl   = (tid >= 512) ? 1 : 0;
    const float* gp = coords + (size_t)b * S_ * T_ + (size_t)srow * T_ + (c0 + scol)
                    + (pl ? plane : (size_t)0);
    float* w0 = &lds[0][pl][srow * LDSP + scol];
    float* w1 = &lds[1][pl][srow * LDSP + scol];

    // lane-distributed sorted lists: lane j (<16) holds slot j of each owned column
    float lv[CPW]; int li[CPW]; float tau[CPW];
#pragma unroll
    for (int cc = 0; cc < CPW; ++cc) {
        lv[cc]  = __int_as_float(0x7f800000);
        li[cc]  = 0;
        tau[cc] = __int_as_float(0x7f800000);
    }

    // prologue: stage tile 0, prefetch tile 1 into registers
    float4 r4 = *(const float4*)gp;
    w0[0] = r4.x; w0[1] = r4.y; w0[2] = r4.z; w0[3] = r4.w;
    r4 = *(const float4*)(gp + (size_t)ROWS * T_);
    __syncthreads();                          // buf0 visible

#pragma unroll 1
    for (int k = 0; k < NTILE; ++k) {
        // stage tile k+1 (held in r4) into buf[(k+1)&1]; issue load of tile k+2
        if (k + 1 < NTILE) {
            float* wb = (k & 1) ? w0 : w1;
            wb[0] = r4.x; wb[1] = r4.y; wb[2] = r4.z; wb[3] = r4.w;
        }
        if (k + 2 < NTILE)
            r4 = *(const float4*)(gp + (size_t)(k + 2) * ROWS * T_);

        // consume tile k from buf[k&1]
        const float* rb0 = lds[k & 1][0];
        const float* rb1 = lds[k & 1][1];
#pragma unroll
        for (int cc = 0; cc < CPW; ++cc) {
            const int col = w * CPW + cc;
            const float dx = rb0[lane * LDSP + col];
            const float dy = rb1[lane * LDSP + col];
            // uncontracted: bit-identical to np's cx*cx + cy*cy
            const float d2 = __fadd_rn(__fmul_rn(dx, dx), __fmul_rn(dy, dy));
            u64 m = __ballot(d2 < tau[cc]);
            while (m) {                       // wave-uniform scalar loop
                const int src = __ffsll(m) - 1;   // lowest lane = smallest s (tie order)
                m &= m - 1;
                const float cd = __shfl(d2, src); // uniform src -> readlane
                const int   ci = k * ROWS + src;
                // insertion position among sorted slots (ties keep existing = smaller idx)
                const unsigned pm = (unsigned)__ballot(lv[cc] <= cd) & 0xFFFFu;
                const int p = __popc(pm);
                const float uv = dpp_shr1_f(lv[cc]);   // VALU shift, lanes 0-15 valid
                const int   ui = dpp_shr1_i(li[cc]);
                const bool here  = (lane == p);
                const bool shift = (lane > p) && (lane < NH_);
                lv[cc] = here ? cd : (shift ? uv : lv[cc]);
                li[cc] = here ? ci : (shift ? ui : li[cc]);
                tau[cc] = __builtin_amdgcn_readlane(__float_as_int(lv[cc]), NH_ - 1)
                              == 0 ? 0.0f : __int_as_float(
                          __builtin_amdgcn_readlane(__float_as_int(lv[cc]), NH_ - 1));
                m &= __ballot(d2 < tau[cc]);  // prune vs tightened threshold
            }
        }
        __syncthreads();                      // buf[(k+1)&1] staged; buf[k&1] free
    }

    // epilogue: write lists + per-wave denom partials
    float dsum = 0.f;
#pragma unroll
    for (int cc = 0; cc < CPW; ++cc) {
        const int t = c0 + w * CPW + cc;
        if (lane < NH_) {
            const float d = sqrtf(lv[cc]) + 1e-15f;
            const float wv = 1.0f / (d * d);
            outW[((size_t)b * T_ + t) * NH_ + lane] = wv;
            outI[((size_t)b * T_ + t) * NH_ + lane] = li[cc];
            dsum += wv;
        }
    }
    if (lane < NH_) red[w * NH_ + lane] = dsum;
    __syncthreads();
    if (tid < NH_) {
        float s = 0.f;
#pragma unroll
        for (int q = 0; q < 16; ++q) s += red[q * NH_ + tid];
        partials[(size_t)bid * NH_ + tid] = s;
    }
}

// ---------------- Kernel B: denom[b][nh] = sum of block partials ----------------
__global__ __launch_bounds__(128) void denom_reduce(
    const float* __restrict__ partials, float* __restrict__ denom)
{
    const int q = blockIdx.x;       // [0,64)
    const int b = q >> 4, j = q & 15;
    const int g = threadIdx.x;      // [0,128) = NCG
    __shared__ float sm[128];
    sm[g] = partials[(size_t)(b * NCG + g) * NH_ + j];
    __syncthreads();
    for (int s = 64; s > 0; s >>= 1) {
        if (g < s) sm[g] += sm[g + s];
        __syncthreads();
    }
    if (g == 0) denom[q] = sm[0];
}

// ---------------- Kernel C: final gather + weighted sum ----------------
__global__ __launch_bounds__(256) void out_kernel(
    const float* __restrict__ x,        // [B][S]
    const float* __restrict__ outW,
    const int*   __restrict__ outI,
    const float* __restrict__ denom,    // [B][NH]
    float* __restrict__ out)            // [B][T]
{
    const int gid = blockIdx.x * 256 + threadIdx.x;  // [0, B*T)
    const int i = gid >> 12;
    const int j = gid & 4095;
    const int ih = j >> 8;
    const size_t base = ((size_t)i * T_ + (size_t)(j & 255) * NH_) * NH_ + ih;
    const int dq = (j & 3) * NH_;
    float acc = 0.f;
#pragma unroll
    for (int k = 0; k < NH_; ++k) {
        float w  = outW[base + (size_t)k * NH_];
        int   id = outI[base + (size_t)k * NH_];
        acc += x[i * S_ + id] * w / denom[dq + k];
    }
    out[gid] = acc;
}

extern "C" void kernel_launch(void* const* d_in, const int* in_sizes, int n_in,
                              void* d_out, int out_size, void* d_ws, size_t ws_size,
                              hipStream_t stream) {
    const float* x      = (const float*)d_in[0];
    const float* coords = (const float*)d_in[1];
    float* out = (float*)d_out;

    float* outW     = (float*)d_ws;                                  // 1 MB
    int*   outI     = (int*)(outW + (size_t)B_ * T_ * NH_);          // 1 MB
    float* partials = (float*)(outI + (size_t)B_ * T_ * NH_);        // 32 KB
    float* denom    = partials + (size_t)(B_ * NCG) * NH_;           // 256 B

    topk_scan   <<<B_ * NCG,      1024, 0, stream>>>(coords, outW, outI, partials);
    denom_reduce<<<64,            128,  0, stream>>>(partials, denom);
    out_kernel  <<<B_ * T_ / 256, 256,  0, stream>>>(x, outW, outI, denom, out);
}

// Round 11
// 131.204 us; speedup vs baseline: 1.6225x; 1.1035x over previous
//
#include <hip/hip_runtime.h>

#define B_ 4
#define S_ 4096
#define T_ 4096
#define NH_ 16
#define CPB 32             // columns per block = 128B rows (full cache lines)
#define CPW 2              // columns per wave (16 waves/block)
#define ROWS 64            // s-rows per LDS tile
#define NTILE (S_ / ROWS)  // 64
#define LDSP 33            // padded LDS row stride (dwords); odd -> bank permutation
#define NCG (T_ / CPB)     // 128 column groups

typedef unsigned long long u64;

// DPP row_shr:1 — shift by one lane within each 16-lane row (VALU-only; replaces
// ds_permute-based __shfl_up on the serial insert critical path). Only lanes 0-15
// are consumed (list slots); other lanes' results are masked off by `shift`.
__device__ __forceinline__ float dpp_shr1_f(float v) {
    return __int_as_float(__builtin_amdgcn_update_dpp(
        0, __float_as_int(v), 0x111 /*row_shr:1*/, 0xF, 0xF, true));
}
__device__ __forceinline__ int dpp_shr1_i(int v) {
    return __builtin_amdgcn_update_dpp(0, v, 0x111, 0xF, 0xF, true);
}

// ---------------- Kernel A: transposed top-16 scan, d2-at-staging ----------------
// grid = B * NCG = 512 blocks x 1024 threads (16 waves) = 2 blocks/CU = 8 waves/SIMD
// (HW cap). Stagers (threads 0-511) load cx4+cy4, compute 4 d2, write 16B to LDS:
// LDS holds d2 only (half the bytes of cx+cy). Double-buffered, 2-tile reg prefetch.
// Consume: wave w owns cols {2w,2w+1}; lanes = 64 s-rows of one column; ballot-skip
// + readlane/DPP insert chain (no LDS-pipe ops on the serial path).
__global__ __launch_bounds__(1024, 8) void topk_scan(
    const float* __restrict__ coords,   // [2][B][S][T]
    float* __restrict__ outW,           // [B][T][NH]
    int*   __restrict__ outI,           // [B][T][NH]
    float* __restrict__ partials)       // [512][NH] per-block denom partials
{
    __shared__ float lds[2][ROWS * LDSP];      // d2 only: 2 x 8.4 KB
    __shared__ float red[16 * NH_];

    const int bid  = blockIdx.x;
    const int b    = bid >> 7;
    const int c0   = (bid & (NCG - 1)) * CPB;
    const int tid  = threadIdx.x;
    const int w    = tid >> 6;
    const int lane = tid & 63;

    const size_t plane = (size_t)B_ * S_ * T_;
    // staging map: stid in [0,512): row = stid>>3, col4 = (stid&7)*4.
    // 8 consecutive threads cover one 128B line (both planes loaded per thread).
    const bool stager = (tid < 512);
    const int  srow = tid >> 3;               // valid for tid<512
    const int  scol = (tid & 7) * 4;
    const float* g0 = coords + (size_t)b * S_ * T_ + (size_t)srow * T_ + (c0 + scol);
    const float* g1 = g0 + plane;
    float* wb0 = &lds[0][srow * LDSP + scol];
    float* wb1 = &lds[1][srow * LDSP + scol];

    // lane-distributed sorted lists: lane j (<16) holds slot j of each owned column
    float lv[CPW]; int li[CPW]; float tau[CPW];
#pragma unroll
    for (int cc = 0; cc < CPW; ++cc) {
        lv[cc]  = __int_as_float(0x7f800000);
        li[cc]  = 0;
        tau[cc] = __int_as_float(0x7f800000);
    }

    // prologue: stage tile 0, prefetch tile 1 into registers
    float4 ax, ay;
    if (stager) {
        ax = *(const float4*)g0;  ay = *(const float4*)g1;
        wb0[0] = __fadd_rn(__fmul_rn(ax.x, ax.x), __fmul_rn(ay.x, ay.x));
        wb0[1] = __fadd_rn(__fmul_rn(ax.y, ax.y), __fmul_rn(ay.y, ay.y));
        wb0[2] = __fadd_rn(__fmul_rn(ax.z, ax.z), __fmul_rn(ay.z, ay.z));
        wb0[3] = __fadd_rn(__fmul_rn(ax.w, ax.w), __fmul_rn(ay.w, ay.w));
        ax = *(const float4*)(g0 + (size_t)ROWS * T_);
        ay = *(const float4*)(g1 + (size_t)ROWS * T_);
    }
    __syncthreads();                          // buf0 visible

#pragma unroll 1
    for (int k = 0; k < NTILE; ++k) {
        // stage tile k+1 (in regs) into buf[(k+1)&1]; issue loads of tile k+2
        if (stager) {
            if (k + 1 < NTILE) {
                float* wb = (k & 1) ? wb0 : wb1;
                wb[0] = __fadd_rn(__fmul_rn(ax.x, ax.x), __fmul_rn(ay.x, ay.x));
                wb[1] = __fadd_rn(__fmul_rn(ax.y, ax.y), __fmul_rn(ay.y, ay.y));
                wb[2] = __fadd_rn(__fmul_rn(ax.z, ax.z), __fmul_rn(ay.z, ay.z));
                wb[3] = __fadd_rn(__fmul_rn(ax.w, ax.w), __fmul_rn(ay.w, ay.w));
            }
            if (k + 2 < NTILE) {
                ax = *(const float4*)(g0 + (size_t)(k + 2) * ROWS * T_);
                ay = *(const float4*)(g1 + (size_t)(k + 2) * ROWS * T_);
            }
        }

        // consume tile k from buf[k&1]
        const float* rb = lds[k & 1];
#pragma unroll
        for (int cc = 0; cc < CPW; ++cc) {
            const int col = w * CPW + cc;
            const float d2 = rb[lane * LDSP + col];
            u64 m = __ballot(d2 < tau[cc]);
            while (m) {                       // wave-uniform scalar loop
                const int src = __ffsll(m) - 1;   // lowest lane = smallest s (tie order)
                m &= m - 1;
                // SGPR-uniform src: readlane (SALU path), NOT ds_bpermute
                const float cd = __int_as_float(
                    __builtin_amdgcn_readlane(__float_as_int(d2), src));
                const int   ci = k * ROWS + src;
                // insertion position among sorted slots (ties keep existing = smaller idx)
                const unsigned pm = (unsigned)__ballot(lv[cc] <= cd) & 0xFFFFu;
                const int p = __popc(pm);
                const float uv = dpp_shr1_f(lv[cc]);   // VALU shift, lanes 0-15 valid
                const int   ui = dpp_shr1_i(li[cc]);
                const bool here  = (lane == p);
                const bool shift = (lane > p) && (lane < NH_);
                lv[cc] = here ? cd : (shift ? uv : lv[cc]);
                li[cc] = here ? ci : (shift ? ui : li[cc]);
                tau[cc] = __int_as_float(
                    __builtin_amdgcn_readlane(__float_as_int(lv[cc]), NH_ - 1));
                m &= __ballot(d2 < tau[cc]);  // prune vs tightened threshold
            }
        }
        __syncthreads();                      // buf[(k+1)&1] staged; buf[k&1] free
    }

    // epilogue: write lists + per-wave denom partials
    float dsum = 0.f;
#pragma unroll
    for (int cc = 0; cc < CPW; ++cc) {
        const int t = c0 + w * CPW + cc;
        if (lane < NH_) {
            const float d = sqrtf(lv[cc]) + 1e-15f;
            const float wv = 1.0f / (d * d);
            outW[((size_t)b * T_ + t) * NH_ + lane] = wv;
            outI[((size_t)b * T_ + t) * NH_ + lane] = li[cc];
            dsum += wv;
        }
    }
    if (lane < NH_) red[w * NH_ + lane] = dsum;
    __syncthreads();
    if (tid < NH_) {
        float s = 0.f;
#pragma unroll
        for (int q = 0; q < 16; ++q) s += red[q * NH_ + tid];
        partials[(size_t)bid * NH_ + tid] = s;
    }
}

// ---------------- Kernel B: denom[b][nh] = sum of block partials ----------------
__global__ __launch_bounds__(128) void denom_reduce(
    const float* __restrict__ partials, float* __restrict__ denom)
{
    const int q = blockIdx.x;       // [0,64)
    const int b = q >> 4, j = q & 15;
    const int g = threadIdx.x;      // [0,128) = NCG
    __shared__ float sm[128];
    sm[g] = partials[(size_t)(b * NCG + g) * NH_ + j];
    __syncthreads();
    for (int s = 64; s > 0; s >>= 1) {
        if (g < s) sm[g] += sm[g + s];
        __syncthreads();
    }
    if (g == 0) denom[q] = sm[0];
}

// ---------------- Kernel C: final gather, 16 threads/output ----------------
__global__ __launch_bounds__(256) void out_kernel(
    const float* __restrict__ x,        // [B][S]
    const float* __restrict__ outW,
    const int*   __restrict__ outI,
    const float* __restrict__ denom,    // [B][NH]
    float* __restrict__ out)            // [B][T]
{
    const int gid16 = blockIdx.x * 256 + threadIdx.x;  // [0, 16*B*T)
    const int oid = gid16 >> 4;
    const int q   = gid16 & 15;
    const int i = oid >> 12;
    const int j = oid & 4095;
    const int ih = j >> 8;
    const size_t base = ((size_t)i * T_ + (size_t)(j & 255) * NH_) * NH_ + ih;
    const float w  = outW[base + (size_t)q * NH_];
    const int   id = outI[base + (size_t)q * NH_];
    float v = x[i * S_ + id] * w / denom[(j & 3) * NH_ + q];
    v += __shfl_xor(v, 1);
    v += __shfl_xor(v, 2);
    v += __shfl_xor(v, 4);
    v += __shfl_xor(v, 8);
    if (q == 0) out[oid] = v;
}

extern "C" void kernel_launch(void* const* d_in, const int* in_sizes, int n_in,
                              void* d_out, int out_size, void* d_ws, size_t ws_size,
                              hipStream_t stream) {
    const float* x      = (const float*)d_in[0];
    const float* coords = (const float*)d_in[1];
    float* out = (float*)d_out;

    float* outW     = (float*)d_ws;                                  // 1 MB
    int*   outI     = (int*)(outW + (size_t)B_ * T_ * NH_);          // 1 MB
    float* partials = (float*)(outI + (size_t)B_ * T_ * NH_);        // 32 KB
    float* denom    = partials + (size_t)(B_ * NCG) * NH_;           // 256 B

    topk_scan   <<<B_ * NCG,           1024, 0, stream>>>(coords, outW, outI, partials);
    denom_reduce<<<64,                 128,  0, stream>>>(partials, denom);
    out_kernel  <<<B_ * T_ * 16 / 256, 256,  0, stream>>>(x, outW, outI, denom, out);
}

// Round 12
// 125.868 us; speedup vs baseline: 1.6913x; 1.0424x over previous
//
#include <hip/hip_runtime.h>

#define B_ 4
#define S_ 4096
#define T_ 4096
#define NH_ 16
#define CPB 32             // columns per block = 128B rows (full cache lines)
#define CPW 2              // columns per wave (16 waves/block)
#define ROWS 64            // s-rows per LDS tile
#define NTILE (S_ / ROWS)  // 64
#define LDSP 33            // padded LDS row stride (dwords); odd -> bank permutation
#define NCG (T_ / CPB)     // 128 column groups

typedef unsigned long long u64;

// DPP row_shr:1 — shift by one lane within each 16-lane row (VALU-only; replaces
// ds_permute-based __shfl_up on the serial insert critical path). Only lanes 0-15
// are consumed (list slots); other lanes' results are masked off by `shift`.
__device__ __forceinline__ float dpp_shr1_f(float v) {
    return __int_as_float(__builtin_amdgcn_update_dpp(
        0, __float_as_int(v), 0x111 /*row_shr:1*/, 0xF, 0xF, true));
}
__device__ __forceinline__ int dpp_shr1_i(int v) {
    return __builtin_amdgcn_update_dpp(0, v, 0x111, 0xF, 0xF, true);
}

// ---------------- Kernel A: transposed top-16 scan ----------------
// grid = B * NCG = 512 blocks x 1024 threads (16 waves) = 2 blocks/CU = 8 waves/SIMD
// (HW cap). Stagers (threads 0-511) load cx4+cy4, compute 4 d2, write 16B to LDS
// (d2 only). Double-buffered, 2-tile reg prefetch.
// Tile 0: cross-lane bitonic sort-64 seeds the sorted-16 directly (the serial
// version would do 64 inserts/column here -- half of ALL inserts). Tiles 1+:
// ballot-skip + readlane/DPP insert chain, prune-free (cd >= lv[15] inserts are
// structural no-ops: p=16 -> no lane<16 writes), tau updated once per tile.
__global__ __launch_bounds__(1024, 8) void topk_scan(
    const float* __restrict__ coords,   // [2][B][S][T]
    float* __restrict__ outW,           // [B][T][NH]
    int*   __restrict__ outI,           // [B][T][NH]
    float* __restrict__ partials)       // [512][NH] per-block denom partials
{
    __shared__ float lds[2][ROWS * LDSP];      // d2 only: 2 x 8.4 KB
    __shared__ float red[16 * NH_];

    const int bid  = blockIdx.x;
    const int b    = bid >> 7;
    const int c0   = (bid & (NCG - 1)) * CPB;
    const int tid  = threadIdx.x;
    const int w    = tid >> 6;
    const int lane = tid & 63;

    const size_t plane = (size_t)B_ * S_ * T_;
    // staging map: tid in [0,512): row = tid>>3, col4 = (tid&7)*4.
    // 8 consecutive threads cover one 128B line (both planes loaded per thread).
    const bool stager = (tid < 512);
    const int  srow = tid >> 3;               // valid for tid<512
    const int  scol = (tid & 7) * 4;
    const float* g0 = coords + (size_t)b * S_ * T_ + (size_t)srow * T_ + (c0 + scol);
    const float* g1 = g0 + plane;
    float* wb0 = &lds[0][srow * LDSP + scol];
    float* wb1 = &lds[1][srow * LDSP + scol];

    // lane-distributed sorted lists: lane j (<16) holds slot j of each owned column
    float lv[CPW]; int li[CPW]; float tau[CPW];
#pragma unroll
    for (int cc = 0; cc < CPW; ++cc) {
        lv[cc]  = __int_as_float(0x7f800000);
        li[cc]  = 0;
        tau[cc] = __int_as_float(0x7f800000);
    }

    // prologue: stage tile 0, prefetch tile 1 into registers
    float4 ax, ay;
    if (stager) {
        ax = *(const float4*)g0;  ay = *(const float4*)g1;
        wb0[0] = __fadd_rn(__fmul_rn(ax.x, ax.x), __fmul_rn(ay.x, ay.x));
        wb0[1] = __fadd_rn(__fmul_rn(ax.y, ax.y), __fmul_rn(ay.y, ay.y));
        wb0[2] = __fadd_rn(__fmul_rn(ax.z, ax.z), __fmul_rn(ay.z, ay.z));
        wb0[3] = __fadd_rn(__fmul_rn(ax.w, ax.w), __fmul_rn(ay.w, ay.w));
        ax = *(const float4*)(g0 + (size_t)ROWS * T_);
        ay = *(const float4*)(g1 + (size_t)ROWS * T_);
    }
    __syncthreads();                          // buf0 visible

#pragma unroll 1
    for (int k = 0; k < NTILE; ++k) {
        // stage tile k+1 (in regs) into buf[(k+1)&1]; issue loads of tile k+2
        if (stager) {
            if (k + 1 < NTILE) {
                float* wb = (k & 1) ? wb0 : wb1;
                wb[0] = __fadd_rn(__fmul_rn(ax.x, ax.x), __fmul_rn(ay.x, ay.x));
                wb[1] = __fadd_rn(__fmul_rn(ax.y, ax.y), __fmul_rn(ay.y, ay.y));
                wb[2] = __fadd_rn(__fmul_rn(ax.z, ax.z), __fmul_rn(ay.z, ay.z));
                wb[3] = __fadd_rn(__fmul_rn(ax.w, ax.w), __fmul_rn(ay.w, ay.w));
            }
            if (k + 2 < NTILE) {
                ax = *(const float4*)(g0 + (size_t)(k + 2) * ROWS * T_);
                ay = *(const float4*)(g1 + (size_t)(k + 2) * ROWS * T_);
            }
        }

        // consume tile k from buf[k&1]
        const float* rb = lds[k & 1];
        if (k == 0) {
            // ---- tile-0 seed: bitonic sort-64 of (d2,s) keys across lanes ----
#pragma unroll
            for (int cc = 0; cc < CPW; ++cc) {
                const float d2 = rb[lane * LDSP + (w * CPW + cc)];
                u64 key = ((u64)(unsigned)__float_as_int(d2) << 32) | (unsigned)lane;
#pragma unroll
                for (int bk = 2; bk <= 64; bk <<= 1) {
#pragma unroll
                    for (int bj = bk >> 1; bj > 0; bj >>= 1) {
                        const u64 o = __shfl_xor(key, bj);
                        const bool takemin = ((lane & bj) == 0) == ((lane & bk) == 0);
                        key = ((key < o) == takemin) ? key : o;
                    }
                }
                // ascending: lane j holds j-th smallest -> exactly slot layout
                lv[cc]  = __int_as_float((int)(unsigned)(key >> 32));
                li[cc]  = (int)(key & 0xFFFFFFFFu);
                tau[cc] = __int_as_float(
                    __builtin_amdgcn_readlane(__float_as_int(lv[cc]), NH_ - 1));
            }
        } else {
#pragma unroll
            for (int cc = 0; cc < CPW; ++cc) {
                const float d2 = rb[lane * LDSP + (w * CPW + cc)];
                u64 m = __ballot(d2 < tau[cc]);
                if (m) {
                    while (m) {                   // wave-uniform scalar loop, prune-free
                        const int src = __ffsll(m) - 1;  // lowest lane = smallest s (ties)
                        m &= m - 1;
                        const float cd = __int_as_float(
                            __builtin_amdgcn_readlane(__float_as_int(d2), src));
                        const int   ci = k * ROWS + src;
                        const unsigned pm = (unsigned)__ballot(lv[cc] <= cd) & 0xFFFFu;
                        const int p = __popc(pm);     // p==16 -> structural no-op
                        const float uv = dpp_shr1_f(lv[cc]);
                        const int   ui = dpp_shr1_i(li[cc]);
                        const bool here  = (lane == p);
                        const bool shift = (lane > p) && (lane < NH_);
                        lv[cc] = here ? cd : (shift ? uv : lv[cc]);
                        li[cc] = here ? ci : (shift ? ui : li[cc]);
                    }
                    tau[cc] = __int_as_float(
                        __builtin_amdgcn_readlane(__float_as_int(lv[cc]), NH_ - 1));
                }
            }
        }
        __syncthreads();                      // buf[(k+1)&1] staged; buf[k&1] free
    }

    // epilogue: write lists + per-wave denom partials
    float dsum = 0.f;
#pragma unroll
    for (int cc = 0; cc < CPW; ++cc) {
        const int t = c0 + w * CPW + cc;
        if (lane < NH_) {
            const float d = sqrtf(lv[cc]) + 1e-15f;
            const float wv = 1.0f / (d * d);
            outW[((size_t)b * T_ + t) * NH_ + lane] = wv;
            outI[((size_t)b * T_ + t) * NH_ + lane] = li[cc];
            dsum += wv;
        }
    }
    if (lane < NH_) red[w * NH_ + lane] = dsum;
    __syncthreads();
    if (tid < NH_) {
        float s = 0.f;
#pragma unroll
        for (int q = 0; q < 16; ++q) s += red[q * NH_ + tid];
        partials[(size_t)bid * NH_ + tid] = s;
    }
}

// ---------------- Kernel B: denom[b][nh] = sum of block partials ----------------
__global__ __launch_bounds__(128) void denom_reduce(
    const float* __restrict__ partials, float* __restrict__ denom)
{
    const int q = blockIdx.x;       // [0,64)
    const int b = q >> 4, j = q & 15;
    const int g = threadIdx.x;      // [0,128) = NCG
    __shared__ float sm[128];
    sm[g] = partials[(size_t)(b * NCG + g) * NH_ + j];
    __syncthreads();
    for (int s = 64; s > 0; s >>= 1) {
        if (g < s) sm[g] += sm[g + s];
        __syncthreads();
    }
    if (g == 0) denom[q] = sm[0];
}

// ---------------- Kernel C: final gather, 16 threads/output ----------------
__global__ __launch_bounds__(256) void out_kernel(
    const float* __restrict__ x,        // [B][S]
    const float* __restrict__ outW,
    const int*   __restrict__ outI,
    const float* __restrict__ denom,    // [B][NH]
    float* __restrict__ out)            // [B][T]
{
    const int gid16 = blockIdx.x * 256 + threadIdx.x;  // [0, 16*B*T)
    const int oid = gid16 >> 4;
    const int q   = gid16 & 15;
    const int i = oid >> 12;
    const int j = oid & 4095;
    const int ih = j >> 8;
    const size_t base = ((size_t)i * T_ + (size_t)(j & 255) * NH_) * NH_ + ih;
    const float w  = outW[base + (size_t)q * NH_];
    const int   id = outI[base + (size_t)q * NH_];
    float v = x[i * S_ + id] * w / denom[(j & 3) * NH_ + q];
    v += __shfl_xor(v, 1);
    v += __shfl_xor(v, 2);
    v += __shfl_xor(v, 4);
    v += __shfl_xor(v, 8);
    if (q == 0) out[oid] = v;
}

extern "C" void kernel_launch(void* const* d_in, const int* in_sizes, int n_in,
                              void* d_out, int out_size, void* d_ws, size_t ws_size,
                              hipStream_t stream) {
    const float* x      = (const float*)d_in[0];
    const float* coords = (const float*)d_in[1];
    float* out = (float*)d_out;

    float* outW     = (float*)d_ws;                                  // 1 MB
    int*   outI     = (int*)(outW + (size_t)B_ * T_ * NH_);          // 1 MB
    float* partials = (float*)(outI + (size_t)B_ * T_ * NH_);        // 32 KB
    float* denom    = partials + (size_t)(B_ * NCG) * NH_;           // 256 B

    topk_scan   <<<B_ * NCG,           1024, 0, stream>>>(coords, outW, outI, partials);
    denom_reduce<<<64,                 128,  0, stream>>>(partials, denom);
    out_kernel  <<<B_ * T_ * 16 / 256, 256,  0, stream>>>(x, outW, outI, denom, out);
}